// Round 5
// baseline (845.391 us; speedup 1.0000x reference)
//
#include <hip/hip_runtime.h>

// WaveletPatcher: 3-level a-trous db4 SWT (periodic) + overlapping patch extract.
// x: (64, 4096, 32) f32  ->  out: (64*511, 32*4, 16) f32
//   A_{l+1}[t] = sum_j LO[j] * A_l[(t + (4-j)*d) & 4095],  d = 2^l
// c=0:A3, 1:D3, 2:D2, 3:D1.  out[(b*511+p)*2048 + n*64 + c*16 + j], t = 8p+j.
//
// R3 lesson: staging all 4 coeff planes costs 39KB LDS (-> 2 blk/CU) and a full
// LDS round-trip re-read in the store phase; kernel ~118us vs ~55us HBM floor.
// R4/R5: merge level-3 with the store. Thread = (n, p_local): computes the whole
// patch's A3/D3 (16 t) from the A2 window, reads staged D1/D2, writes the full
// 256B [A3|D3|D2|D1] group contiguously (nontemporal). LDS 51.2KB -> 3 blk/CU.
// (R4 failed only on __builtin_nontemporal_store rejecting HIP float4 -> use
// clang ext_vector_type.)

#define NTHREADS 256
#define T_MASK   4095

typedef float floatx4 __attribute__((ext_vector_type(4)));  // native vec for builtins

// float strides/offsets in the shared pool (padded, all quad-aligned)
#define S_IN  132   // IN covers trel [-23, 104], idx = trel+23
#define S_A1  116   // A1 covers trel [-20, 95],  idx = trel+20
#define S_A2  108   // A2 covers trel [-12, 87],  idx = trel+12  (aliases IN)
#define S_ST  76    // D1/D2 stage, trel [0, 71]
#define OFF_IN 0
#define OFF_A1 4224                  // 32*132
#define OFF_A2 0                     // alias IN (x dead after level 1)
#define OFF_D1 7936                  // 4224 + 32*116
#define OFF_D2 10368                 // + 32*76
#define LDS_FLOATS 12800             // + 32*76 = 51200 B -> 3 blocks/CU

__device__ __constant__ float c_lo[8] = {
    -0.010597401784997278f, 0.032883011666982945f, 0.030841381835986965f,
    -0.18703481171888114f, -0.02798376941698385f, 0.6308807679295904f,
    0.7148465705525415f,   0.23037781330885523f};
__device__ __constant__ float c_hi[8] = {
    -0.23037781330885523f, 0.7148465705525415f, -0.6308807679295904f,
    -0.02798376941698385f, 0.18703481171888114f, 0.030841381835986965f,
    -0.032883011666982945f, -0.010597401784997278f};

__global__ __launch_bounds__(NTHREADS, 3) void swt_patch(const float* __restrict__ x,
                                                         float* __restrict__ out) {
    __shared__ float lds[LDS_FLOATS];

    const int blk = blockIdx.x;        // 0..4095
    const int b   = blk >> 6;          // 0..63
    const int cid = blk & 63;          // chunk id
    const int T0  = cid << 6;          // first patch-start t
    const int p0  = cid << 3;          // first patch index (8 per chunk)
    const int tid = threadIdx.x;

    // ---- phase 0: load x[b, T0-23 .. T0+104, all n] coalesced, transpose to IN[n][.] ----
    const float* xb = x + (size_t)b * (4096 * 32);
#pragma unroll
    for (int it = 0; it < 4; ++it) {
        const int id = tid + it * NTHREADS;        // 0..1023
        const int i  = id >> 3;                    // t-window idx 0..127
        const int n0 = (id & 7) * 4;
        const int t  = (T0 - 23 + i) & T_MASK;
        const floatx4 v = *(const floatx4*)&xb[(size_t)t * 32 + n0];
        lds[OFF_IN + (n0 + 0) * S_IN + i] = v.x;
        lds[OFF_IN + (n0 + 1) * S_IN + i] = v.y;
        lds[OFF_IN + (n0 + 2) * S_IN + i] = v.z;
        lds[OFF_IN + (n0 + 3) * S_IN + i] = v.w;
    }
    __syncthreads();

    // ---- level 1 (d=1): IN -> A1 (trel -20..95); D1 -> stage (trel 0..71) ----
    for (int tsk = tid; tsk < 29 * 32; tsk += NTHREADS) {
        const int n = tsk & 31, q = tsk >> 5;
        const int trel0 = -20 + 4 * q;
        float w[12];
        const int base = OFF_IN + n * S_IN + 4 * q;   // IN idx 4q <-> trel trel0-3
        *(floatx4*)&w[0] = *(const floatx4*)&lds[base];
        *(floatx4*)&w[4] = *(const floatx4*)&lds[base + 4];
        *(floatx4*)&w[8] = *(const floatx4*)&lds[base + 8];
        floatx4 va, vd;
#pragma unroll
        for (int ii = 0; ii < 4; ++ii) {
            float sa = 0.f, sd = 0.f;
#pragma unroll
            for (int j = 0; j < 8; ++j) {             // tap trel0+ii+(4-j) -> w[ii+7-j]
                const float v = w[ii + 7 - j];
                sa = fmaf(c_lo[j], v, sa);
                sd = fmaf(c_hi[j], v, sd);
            }
            va[ii] = sa; vd[ii] = sd;
        }
        *(floatx4*)&lds[OFF_A1 + n * S_A1 + (trel0 + 20)] = va;
        if (trel0 >= 0 && trel0 <= 68)
            *(floatx4*)&lds[OFF_D1 + n * S_ST + trel0] = vd;
    }
    __syncthreads();

    // ---- level 2 (d=2): A1 -> A2 (trel -12..87, aliases IN); D2 -> stage ----
    for (int tsk = tid; tsk < 25 * 32; tsk += NTHREADS) {
        const int n = tsk & 31, q = tsk >> 5;
        const int trel0 = -12 + 4 * q;
        float w[20];
        const int base = OFF_A1 + n * S_A1 + 4 * q;   // A1 idx 4q <-> trel trel0-8
#pragma unroll
        for (int c4 = 0; c4 < 5; ++c4)
            *(floatx4*)&w[4 * c4] = *(const floatx4*)&lds[base + 4 * c4];
        floatx4 va, vd;
#pragma unroll
        for (int ii = 0; ii < 4; ++ii) {
            float sa = 0.f, sd = 0.f;
#pragma unroll
            for (int j = 0; j < 8; ++j) {             // tap trel0+ii+2(4-j) -> w[ii+16-2j]
                const float v = w[ii + 16 - 2 * j];
                sa = fmaf(c_lo[j], v, sa);
                sd = fmaf(c_hi[j], v, sd);
            }
            va[ii] = sa; vd[ii] = sd;
        }
        *(floatx4*)&lds[OFF_A2 + n * S_A2 + (trel0 + 12)] = va;
        if (trel0 >= 0 && trel0 <= 68)
            *(floatx4*)&lds[OFF_D2 + n * S_ST + trel0] = vd;
    }
    __syncthreads();

    // ---- level 3 (d=4) merged with store: thread = (n, p_local) ----
    // Computes A3/D3 for all 16 t of its patch, reads staged D1/D2, writes the
    // full 256B group [A3|D3|D2|D1] contiguously. Wave = 16KB contiguous.
    {
        const int n = tid & 31, p = tid >> 5;          // p 0..7
        // A2 window: trel 8p-12 .. 8p+31  -> A2 idx 8p .. 8p+43 (11 aligned float4)
        float w[44];
        const int base = OFF_A2 + n * S_A2 + 8 * p;
#pragma unroll
        for (int c4 = 0; c4 < 11; ++c4)
            *(floatx4*)&w[4 * c4] = *(const floatx4*)&lds[base + 4 * c4];

        float coef[64];                                // [A3(16) | D3(16) | D2(16) | D1(16)]
#pragma unroll
        for (int jj = 0; jj < 16; ++jj) {
            float sa = 0.f, sd = 0.f;
#pragma unroll
            for (int j = 0; j < 8; ++j) {              // tap t=8p+jj+4(4-j) -> w[jj+28-4j]
                const float v = w[jj + 28 - 4 * j];
                sa = fmaf(c_lo[j], v, sa);
                sd = fmaf(c_hi[j], v, sd);
            }
            coef[jj]      = sa;                        // A3
            coef[16 + jj] = sd;                        // D3
        }
        const int sbase = n * S_ST + 8 * p;            // staged trel 8p..8p+15
#pragma unroll
        for (int c4 = 0; c4 < 4; ++c4) {
            *(floatx4*)&coef[32 + 4 * c4] = *(const floatx4*)&lds[OFF_D2 + sbase + 4 * c4];
            *(floatx4*)&coef[48 + 4 * c4] = *(const floatx4*)&lds[OFF_D1 + sbase + 4 * c4];
        }
        if (p0 + p < 511) {
            floatx4* dst = (floatx4*)(out + ((size_t)b * 511 + p0 + p) * 2048 + n * 64);
#pragma unroll
            for (int s = 0; s < 16; ++s)
                __builtin_nontemporal_store(*(const floatx4*)&coef[4 * s], dst + s);
        }
    }
}

extern "C" void kernel_launch(void* const* d_in, const int* in_sizes, int n_in,
                              void* d_out, int out_size, void* d_ws, size_t ws_size,
                              hipStream_t stream) {
    const float* x = (const float*)d_in[0];
    float* out = (float*)d_out;
    hipLaunchKernelGGL(swt_patch, dim3(64 * 64), dim3(NTHREADS), 0, stream, x, out);
}